// Round 2
// baseline (16075.465 us; speedup 1.0000x reference)
//
#include <hip/hip_runtime.h>
#include <hip/hip_bf16.h>

typedef unsigned short u16;
typedef unsigned int   u32;

#define NB    256      // blocks == CUs, all co-resident (persistent kernel)
#define NT    512      // threads/block = 8 waves
#define HD    1024
#define G4    4096
#define VOCAB 32000
#define EDIM  512
#define SLEN  512
#define RPB   (VOCAB / NB)   // 125 fc rows per block

// ---------- bf16 helpers ----------
__device__ __forceinline__ float bflo(u32 u){ union{u32 i; float f;} v; v.i = u << 16; return v.f; }
__device__ __forceinline__ float bfhi(u32 u){ union{u32 i; float f;} v; v.i = u & 0xffff0000u; return v.f; }
__device__ __forceinline__ float bf1(u16 u){ union{u32 i; float f;} v; v.i = ((u32)u) << 16; return v.f; }
__device__ __forceinline__ u16 f2bf(float f){
    union{float f; u32 i;} v; v.f = f;
    u32 x = v.i;
    u32 r = (x + 0x7fffu + ((x >> 16) & 1u)) >> 16;   // RNE
    return (u16)r;
}

__device__ __forceinline__ float sigm(float x){ return 1.f / (1.f + __expf(-x)); }
__device__ __forceinline__ float tanh_f(float x){ float e = __expf(2.f * x); return 1.f - 2.f / (e + 1.f); }

// ---------- wave-wide sum (64 lanes) ----------
__device__ __forceinline__ float wave_sum(float v){
#pragma unroll
    for (int off = 32; off > 0; off >>= 1) v += __shfl_xor(v, off, 64);
    return v;
}

__device__ __forceinline__ float dot16bf(uint4 a, uint4 b, const float* h){
    float s = 0.f;
    s = fmaf(bflo(a.x), h[0],  s); s = fmaf(bfhi(a.x), h[1],  s);
    s = fmaf(bflo(a.y), h[2],  s); s = fmaf(bfhi(a.y), h[3],  s);
    s = fmaf(bflo(a.z), h[4],  s); s = fmaf(bfhi(a.z), h[5],  s);
    s = fmaf(bflo(a.w), h[6],  s); s = fmaf(bfhi(a.w), h[7],  s);
    s = fmaf(bflo(b.x), h[8],  s); s = fmaf(bfhi(b.x), h[9],  s);
    s = fmaf(bflo(b.y), h[10], s); s = fmaf(bfhi(b.y), h[11], s);
    s = fmaf(bflo(b.z), h[12], s); s = fmaf(bfhi(b.z), h[13], s);
    s = fmaf(bflo(b.w), h[14], s); s = fmaf(bfhi(b.w), h[15], s);
    return s;
}

__device__ __forceinline__ void load16(const float* src, int lane, float* d){
    const float4* p = (const float4*)(src + (lane << 4));
    float4 a = p[0], b = p[1], c = p[2], e = p[3];
    d[0]=a.x; d[1]=a.y; d[2]=a.z; d[3]=a.w;
    d[4]=b.x; d[5]=b.y; d[6]=b.z; d[7]=b.w;
    d[8]=c.x; d[9]=c.y; d[10]=c.z; d[11]=c.w;
    d[12]=e.x; d[13]=e.y; d[14]=e.z; d[15]=e.w;
}

// ---------- dtype traits ----------
struct TBF {
    static __device__ __forceinline__ float g(const void* p, int i){ return bf1(((const u16*)p)[i]); }
    static __device__ __forceinline__ const void* rp(const void* p, size_t eoff){ return (const void*)((const u16*)p + eoff); }
    static __device__ __forceinline__ float dot1024(const void* pr, const float* h, int lane){
        const u16* row = (const u16*)pr;
        const uint4* p = (const uint4*)(row + ((size_t)lane << 4));
        uint4 a = p[0], b = p[1];
        return dot16bf(a, b, h);
    }
    static __device__ __forceinline__ float dot512(const void* pr, const float* h8, int lane){
        const u16* row = (const u16*)pr;
        uint4 a = *((const uint4*)(row + ((size_t)lane << 3)));
        float s = 0.f;
        s = fmaf(bflo(a.x), h8[0], s); s = fmaf(bfhi(a.x), h8[1], s);
        s = fmaf(bflo(a.y), h8[2], s); s = fmaf(bfhi(a.y), h8[3], s);
        s = fmaf(bflo(a.z), h8[4], s); s = fmaf(bfhi(a.z), h8[5], s);
        s = fmaf(bflo(a.w), h8[6], s); s = fmaf(bfhi(a.w), h8[7], s);
        return s;
    }
    static __device__ __forceinline__ void vec8(const void* pr, int lane, float* d){
        const u16* src = (const u16*)pr;
        uint4 a = *((const uint4*)(src + ((size_t)lane << 3)));
        d[0]=bflo(a.x); d[1]=bfhi(a.x); d[2]=bflo(a.y); d[3]=bfhi(a.y);
        d[4]=bflo(a.z); d[5]=bfhi(a.z); d[6]=bflo(a.w); d[7]=bfhi(a.w);
    }
    static __device__ __forceinline__ void store(void* o, size_t i, float v){ ((u16*)o)[i] = f2bf(v); }
    static __device__ __forceinline__ void zero(void* o, size_t i){ ((u16*)o)[i] = 0; }
};

struct TF32 {
    static __device__ __forceinline__ float g(const void* p, int i){ return ((const float*)p)[i]; }
    static __device__ __forceinline__ const void* rp(const void* p, size_t eoff){ return (const void*)((const float*)p + eoff); }
    static __device__ __forceinline__ float dot1024(const void* pr, const float* h, int lane){
        const float4* p = (const float4*)((const float*)pr + ((size_t)lane << 4));
        float4 a = p[0], b = p[1], c = p[2], e = p[3];
        float s = 0.f;
        s = fmaf(a.x, h[0],  s); s = fmaf(a.y, h[1],  s); s = fmaf(a.z, h[2],  s); s = fmaf(a.w, h[3],  s);
        s = fmaf(b.x, h[4],  s); s = fmaf(b.y, h[5],  s); s = fmaf(b.z, h[6],  s); s = fmaf(b.w, h[7],  s);
        s = fmaf(c.x, h[8],  s); s = fmaf(c.y, h[9],  s); s = fmaf(c.z, h[10], s); s = fmaf(c.w, h[11], s);
        s = fmaf(e.x, h[12], s); s = fmaf(e.y, h[13], s); s = fmaf(e.z, h[14], s); s = fmaf(e.w, h[15], s);
        return s;
    }
    static __device__ __forceinline__ float dot512(const void* pr, const float* h8, int lane){
        const float4* p = (const float4*)((const float*)pr + ((size_t)lane << 3));
        float4 a = p[0], b = p[1];
        float s = 0.f;
        s = fmaf(a.x, h8[0], s); s = fmaf(a.y, h8[1], s); s = fmaf(a.z, h8[2], s); s = fmaf(a.w, h8[3], s);
        s = fmaf(b.x, h8[4], s); s = fmaf(b.y, h8[5], s); s = fmaf(b.z, h8[6], s); s = fmaf(b.w, h8[7], s);
        return s;
    }
    static __device__ __forceinline__ void vec8(const void* pr, int lane, float* d){
        const float4* p = (const float4*)((const float*)pr + ((size_t)lane << 3));
        float4 a = p[0], b = p[1];
        d[0]=a.x; d[1]=a.y; d[2]=a.z; d[3]=a.w;
        d[4]=b.x; d[5]=b.y; d[6]=b.z; d[7]=b.w;
    }
    static __device__ __forceinline__ void store(void* o, size_t i, float v){ ((float*)o)[i] = v; }
    static __device__ __forceinline__ void zero(void* o, size_t i){ ((float*)o)[i] = 0.f; }
};

// ---------- two-level monotonic grid barrier ----------
__device__ __forceinline__ void grid_barrier(u32* bar, u32 tgen, int bid){
    __syncthreads();
    if (threadIdx.x == 0){
        __builtin_amdgcn_fence(__ATOMIC_RELEASE, "agent");
        u32 a = __hip_atomic_fetch_add(&bar[(bid & 7) * 32], 1u,
                                       __ATOMIC_RELAXED, __HIP_MEMORY_SCOPE_AGENT);
        if ((a % 32u) == 31u){
            u32 m = __hip_atomic_fetch_add(&bar[256], 1u,
                                           __ATOMIC_RELAXED, __HIP_MEMORY_SCOPE_AGENT);
            if ((m % 8u) == 7u)
                __hip_atomic_store(&bar[288], tgen, __ATOMIC_RELAXED, __HIP_MEMORY_SCOPE_AGENT);
        }
        while (__hip_atomic_load(&bar[288], __ATOMIC_RELAXED, __HIP_MEMORY_SCOPE_AGENT) < tgen)
            __builtin_amdgcn_s_sleep(1);
        __builtin_amdgcn_fence(__ATOMIC_ACQUIRE, "agent");
    }
    __syncthreads();
}

__global__ void ws_init(u32* ws){
    int i = threadIdx.x + blockIdx.x * blockDim.x;
    if (i < 1024) ws[i] = 0u;
}

// probe: decide bf16 (0) vs f32 (1) by scanning emb's u16s as bf16 exponents.
// bf16 weights (~0.03 scale) never have |v|>=8; random f32 low-halves do ~50%.
__global__ void dtype_probe(const u16* emb, u32* ws){
    __shared__ int sh[4];
    int tid = threadIdx.x;
    int bad = 0;
    for (int i = tid; i < 2048; i += 256){
        u32 e = ((u32)emb[i] >> 7) & 0xFFu;
        if (e >= 0x82u) bad++;
    }
#pragma unroll
    for (int off = 32; off > 0; off >>= 1) bad += __shfl_xor(bad, off, 64);
    if ((tid & 63) == 0) sh[tid >> 6] = bad;
    __syncthreads();
    if (tid == 0){
        int t = sh[0] + sh[1] + sh[2] + sh[3];
        ws[512] = (t > 8) ? 1u : 0u;
    }
}

template<class W, u32 WANT>
__global__ __launch_bounds__(NT) void dae_main(
    const int* __restrict__ xs, const int* __restrict__ ys,
    const void* __restrict__ emb,
    const void* __restrict__ eWih0, const void* __restrict__ eWhh0,
    const void* __restrict__ ebih0, const void* __restrict__ ebhh0,
    const void* __restrict__ eWih1, const void* __restrict__ eWhh1,
    const void* __restrict__ ebih1, const void* __restrict__ ebhh1,
    const void* __restrict__ efcW,  const void* __restrict__ efcb,
    const void* __restrict__ dWih0, const void* __restrict__ dWhh0,
    const void* __restrict__ dbih0, const void* __restrict__ dbhh0,
    const void* __restrict__ dWih1, const void* __restrict__ dWhh1,
    const void* __restrict__ dbih1, const void* __restrict__ dbhh1,
    const void* __restrict__ dfcW,  const void* __restrict__ dfcb,
    void* __restrict__ out, u32* __restrict__ ws)
{
    if (__hip_atomic_load(&ws[512], __ATOMIC_RELAXED, __HIP_MEMORY_SCOPE_AGENT) != WANT) return;

    const int tid  = threadIdx.x;
    const int bid  = blockIdx.x;
    const int lane = tid & 63;
    const int wave = tid >> 6;

    __shared__ __align__(16) float h0s[HD];
    __shared__ __align__(16) float h1s[HD];
    __shared__ float redmax[8];
    __shared__ int   redidx[8];
    __shared__ float xf_sh;

    u32*   bar  = ws;
    float* G0   = (float*)(ws + 1024);   // [2][4096]
    float* G1   = G0 + 2 * G4;           // [2][4096]
    float* M0   = G1 + 2 * G4;           // [2][4096]
    float* Fv   = M0 + 2 * G4;           // [1024]
    float* bmax = Fv + HD;               // [256]
    int*   bidxv= (int*)(bmax + NB);     // [256]

    u32 phase = 0;
    float c0r[2] = {0.f, 0.f};
    float c1r[2] = {0.f, 0.f};

    for (int i = tid; i < HD; i += NT){ h0s[i] = 0.f; h1s[i] = 0.f; }
    for (int i = tid; i < RPB; i += NT) W::zero(out, (size_t)bid * RPB + i);   // row 0 = zeros

    // ---------------- boot: G0[0] = eWih0 @ emb[x0] + b0 ----------------
    {
        int tok = xs[0];
        float er[8];
        W::vec8(W::rp(emb, (size_t)tok * EDIM), lane, er);
        const int rb = bid * 16 + wave * 2;
#pragma unroll
        for (int i = 0; i < 2; ++i){
            int r = rb + i;
            float s = W::dot512(W::rp(eWih0, (size_t)r * EDIM), er, lane);
            s = wave_sum(s);
            if (lane == 0) G0[r] = s + W::g(ebih0, r) + W::g(ebhh0, r);
        }
    }
    grid_barrier(bar, ++phase, bid);

    // ---------------- encoder: 1 phase per step (layer-1 lags one step) --
    for (int t = 0; t < SLEN; ++t){
        const int cur = t & 1, nxt = cur ^ 1;
        if (t >= 1){
            const float* Gg = G1 + nxt * G4;
#pragma unroll
            for (int i = 0; i < 2; ++i){
                int r = tid * 2 + i;
                float ig = Gg[r], fg = Gg[r + HD], gg = Gg[r + 2*HD], og = Gg[r + 3*HD];
                float c = sigm(fg) * c1r[i] + sigm(ig) * tanh_f(gg);
                c1r[i] = c;
                h1s[r] = sigm(og) * tanh_f(c);
            }
        }
        {
            const float* Gg = G0 + cur * G4;
#pragma unroll
            for (int i = 0; i < 2; ++i){
                int r = tid * 2 + i;
                float ig = Gg[r], fg = Gg[r + HD], gg = Gg[r + 2*HD], og = Gg[r + 3*HD];
                float c = sigm(fg) * c0r[i] + sigm(ig) * tanh_f(gg);
                c0r[i] = c;
                h0s[r] = sigm(og) * tanh_f(c);
            }
        }
        __syncthreads();
        float h0r[16], h1r[16];
        load16(h0s, lane, h0r);
        load16(h1s, lane, h1r);
        const int rb = bid * 16 + wave * 2;
        if (t < SLEN - 1){
            int tok = xs[t + 1];
            float er[8];
            W::vec8(W::rp(emb, (size_t)tok * EDIM), lane, er);
#pragma unroll
            for (int i = 0; i < 2; ++i){
                int r = rb + i;
                float s = W::dot1024(W::rp(eWhh0, (size_t)r * HD), h0r, lane)
                        + W::dot512(W::rp(eWih0, (size_t)r * EDIM), er, lane);
                s = wave_sum(s);
                if (lane == 0) G0[nxt * G4 + r] = s + W::g(ebih0, r) + W::g(ebhh0, r);
            }
        }
#pragma unroll
        for (int i = 0; i < 2; ++i){
            int r = rb + i;
            float s = W::dot1024(W::rp(eWih1, (size_t)r * HD), h0r, lane)
                    + W::dot1024(W::rp(eWhh1, (size_t)r * HD), h1r, lane);
            s = wave_sum(s);
            if (lane == 0) G1[cur * G4 + r] = s + W::g(ebih1, r) + W::g(ebhh1, r);
        }
        grid_barrier(bar, ++phase, bid);
    }

    // ---------------- encoder final: h1[511]; F = efcW @ h1 + efcb -------
    {
        const float* Gg = G1 + ((SLEN - 1) & 1) * G4;
#pragma unroll
        for (int i = 0; i < 2; ++i){
            int r = tid * 2 + i;
            float ig = Gg[r], fg = Gg[r + HD], gg = Gg[r + 2*HD], og = Gg[r + 3*HD];
            float c = sigm(fg) * c1r[i] + sigm(ig) * tanh_f(gg);
            c1r[i] = c;
            h1s[r] = sigm(og) * tanh_f(c);
        }
        __syncthreads();
        float h1r[16];
        load16(h1s, lane, h1r);
        if (wave < 4){
            int r = bid * 4 + wave;
            float s = W::dot1024(W::rp(efcW, (size_t)r * HD), h1r, lane);
            s = wave_sum(s);
            if (lane == 0) Fv[r] = s + W::g(efcb, r);
        }
        grid_barrier(bar, ++phase, bid);
    }

    // ---------------- decoder boot: lat = relu(F); M0[1] = dWhh0@lat + b0
    {
        for (int i = tid; i < HD; i += NT){
            float v = Fv[i]; v = v > 0.f ? v : 0.f;
            h0s[i] = v; h1s[i] = v;
        }
        __syncthreads();
        float h0r[16];
        load16(h0s, lane, h0r);
        const int rb = bid * 16 + wave * 2;
#pragma unroll
        for (int i = 0; i < 2; ++i){
            int r = rb + i;
            float s = W::dot1024(W::rp(dWhh0, (size_t)r * HD), h0r, lane);
            s = wave_sum(s);
            if (lane == 0) M0[G4 + r] = s + W::g(dbih0, r) + W::g(dbhh0, r);
        }
        grid_barrier(bar, ++phase, bid);
    }

    // ---------------- decoder: 2 phases per step -------------------------
    for (int t = 1; t < 256; ++t){
        // ---- phase P(t): x_f, h0(t); G1d(t), M0(t+1) ----
        float xf;
        if (t == 1){
            xf = (float)ys[0];
        } else {
            if (wave == 0){
                float m = bmax[lane]; int mi = bidxv[lane];
#pragma unroll
                for (int j = 64; j < NB; j += 64){
                    float m2 = bmax[lane + j]; int i2 = bidxv[lane + j];
                    if (m2 > m || (m2 == m && i2 < mi)){ m = m2; mi = i2; }
                }
#pragma unroll
                for (int off = 32; off > 0; off >>= 1){
                    float m2 = __shfl_xor(m, off, 64);
                    int   i2 = __shfl_xor(mi, off, 64);
                    if (m2 > m || (m2 == m && i2 < mi)){ m = m2; mi = i2; }
                }
                if (lane == 0) xf_sh = (float)mi;
            }
            __syncthreads();
            xf = xf_sh;
        }
        {
            const float* Gg = M0 + (t & 1) * G4;
#pragma unroll
            for (int i = 0; i < 2; ++i){
                int r = tid * 2 + i;
                float ig = Gg[r]        + xf * W::g(dWih0, r);
                float fg = Gg[r + HD]   + xf * W::g(dWih0, r + HD);
                float gg = Gg[r + 2*HD] + xf * W::g(dWih0, r + 2*HD);
                float og = Gg[r + 3*HD] + xf * W::g(dWih0, r + 3*HD);
                float cp = h0s[r];                       // quirk: c := h
                float c  = sigm(fg) * cp + sigm(ig) * tanh_f(gg);
                h0s[r]   = sigm(og) * tanh_f(c);
            }
        }
        __syncthreads();
        {
            float h0r[16], h1r[16];
            load16(h0s, lane, h0r);
            load16(h1s, lane, h1r);
            const int rb = bid * 16 + wave * 2;
#pragma unroll
            for (int i = 0; i < 2; ++i){
                int r = rb + i;
                float s1 = W::dot1024(W::rp(dWih1, (size_t)r * HD), h0r, lane)
                         + W::dot1024(W::rp(dWhh1, (size_t)r * HD), h1r, lane);
                s1 = wave_sum(s1);
                if (lane == 0) G1[(t & 1) * G4 + r] = s1 + W::g(dbih1, r) + W::g(dbhh1, r);
                float s0 = W::dot1024(W::rp(dWhh0, (size_t)r * HD), h0r, lane);
                s0 = wave_sum(s0);
                if (lane == 0) M0[((t + 1) & 1) * G4 + r] = s0 + W::g(dbih0, r) + W::g(dbhh0, r);
            }
        }
        grid_barrier(bar, ++phase, bid);

        // ---- phase Q(t): h1(t); logits(t) + per-block argmax ----
        {
            const float* Gg = G1 + (t & 1) * G4;
#pragma unroll
            for (int i = 0; i < 2; ++i){
                int r = tid * 2 + i;
                float ig = Gg[r], fg = Gg[r + HD], gg = Gg[r + 2*HD], og = Gg[r + 3*HD];
                float cp = h1s[r];                       // quirk: c := h
                float c  = sigm(fg) * cp + sigm(ig) * tanh_f(gg);
                h1s[r]   = sigm(og) * tanh_f(c);
            }
        }
        __syncthreads();
        {
            float h1r[16];
            load16(h1s, lane, h1r);
            float wmax = -3.4e38f; int wmi = 0x7fffffff;
            for (int i = wave; i < RPB; i += 8){
                int r = bid * RPB + i;
                float s = W::dot1024(W::rp(dfcW, (size_t)r * HD), h1r, lane);
                s = wave_sum(s) + W::g(dfcb, r);
                if (lane == 0) W::store(out, (size_t)t * VOCAB + r, s);
                if (s > wmax){ wmax = s; wmi = r; }      // rows ascending: tie keeps first
            }
            if (lane == 0){ redmax[wave] = wmax; redidx[wave] = wmi; }
        }
        __syncthreads();
        if (tid == 0){
            float m = redmax[0]; int mi = redidx[0];
#pragma unroll
            for (int w = 1; w < 8; ++w){
                if (redmax[w] > m || (redmax[w] == m && redidx[w] < mi)){ m = redmax[w]; mi = redidx[w]; }
            }
            bmax[bid] = m; bidxv[bid] = mi;
        }
        grid_barrier(bar, ++phase, bid);
    }
}

extern "C" void kernel_launch(void* const* d_in, const int* in_sizes, int n_in,
                              void* d_out, int out_size, void* d_ws, size_t ws_size,
                              hipStream_t stream) {
    const int* xs = (const int*)d_in[0];
    const int* ys = (const int*)d_in[1];
    u32* ws = (u32*)d_ws;

    ws_init<<<4, 256, 0, stream>>>(ws);
    dtype_probe<<<1, 256, 0, stream>>>((const u16*)d_in[2], ws);

    dae_main<TBF, 0u><<<NB, NT, 0, stream>>>(
        xs, ys, d_in[2],
        d_in[3], d_in[4], d_in[5], d_in[6], d_in[7], d_in[8], d_in[9], d_in[10],
        d_in[11], d_in[12],
        d_in[13], d_in[14], d_in[15], d_in[16], d_in[17], d_in[18], d_in[19], d_in[20],
        d_in[21], d_in[22],
        d_out, ws);
    dae_main<TF32, 1u><<<NB, NT, 0, stream>>>(
        xs, ys, d_in[2],
        d_in[3], d_in[4], d_in[5], d_in[6], d_in[7], d_in[8], d_in[9], d_in[10],
        d_in[11], d_in[12],
        d_in[13], d_in[14], d_in[15], d_in[16], d_in[17], d_in[18], d_in[19], d_in[20],
        d_in[21], d_in[22],
        d_out, ws);
}

// Round 3
// 13576.924 us; speedup vs baseline: 1.1840x; 1.1840x over previous
//
#include <hip/hip_runtime.h>
#include <hip/hip_bf16.h>

typedef unsigned short u16;
typedef unsigned int   u32;

#define NB    256      // blocks == CUs, all co-resident (persistent kernel)
#define NT    512      // threads/block = 8 waves
#define HD    1024
#define G4    4096
#define VOCAB 32000
#define EDIM  512
#define SLEN  512
#define RPB   (VOCAB / NB)   // 125 fc rows per block

// ---------- bf16 helpers ----------
__device__ __forceinline__ float bflo(u32 u){ union{u32 i; float f;} v; v.i = u << 16; return v.f; }
__device__ __forceinline__ float bfhi(u32 u){ union{u32 i; float f;} v; v.i = u & 0xffff0000u; return v.f; }
__device__ __forceinline__ float bf1(u16 u){ union{u32 i; float f;} v; v.i = ((u32)u) << 16; return v.f; }
__device__ __forceinline__ u16 f2bf(float f){
    union{float f; u32 i;} v; v.f = f;
    u32 x = v.i;
    u32 r = (x + 0x7fffu + ((x >> 16) & 1u)) >> 16;   // RNE
    return (u16)r;
}

__device__ __forceinline__ float sigm(float x){ return 1.f / (1.f + __expf(-x)); }
__device__ __forceinline__ float tanh_f(float x){ float e = __expf(2.f * x); return 1.f - 2.f / (e + 1.f); }

// ---------- coherent (cross-XCD) access without cache-wide invalidation ----
// agent-scope relaxed atomics -> sc1 load/store: per-line coherent, leaves
// the rest of L2 (all the read-only weights) untouched.
__device__ __forceinline__ float gldf(const float* p){
    return __hip_atomic_load(p, __ATOMIC_RELAXED, __HIP_MEMORY_SCOPE_AGENT);
}
__device__ __forceinline__ void gstf(float* p, float v){
    __hip_atomic_store(p, v, __ATOMIC_RELAXED, __HIP_MEMORY_SCOPE_AGENT);
}
__device__ __forceinline__ int gldi(const int* p){
    return __hip_atomic_load(p, __ATOMIC_RELAXED, __HIP_MEMORY_SCOPE_AGENT);
}
__device__ __forceinline__ void gsti(int* p, int v){
    __hip_atomic_store(p, v, __ATOMIC_RELAXED, __HIP_MEMORY_SCOPE_AGENT);
}

// ---------- wave-wide sum (64 lanes) ----------
__device__ __forceinline__ float wave_sum(float v){
#pragma unroll
    for (int off = 32; off > 0; off >>= 1) v += __shfl_xor(v, off, 64);
    return v;
}

__device__ __forceinline__ float dot16bf(uint4 a, uint4 b, const float* h){
    float s = 0.f;
    s = fmaf(bflo(a.x), h[0],  s); s = fmaf(bfhi(a.x), h[1],  s);
    s = fmaf(bflo(a.y), h[2],  s); s = fmaf(bfhi(a.y), h[3],  s);
    s = fmaf(bflo(a.z), h[4],  s); s = fmaf(bfhi(a.z), h[5],  s);
    s = fmaf(bflo(a.w), h[6],  s); s = fmaf(bfhi(a.w), h[7],  s);
    s = fmaf(bflo(b.x), h[8],  s); s = fmaf(bfhi(b.x), h[9],  s);
    s = fmaf(bflo(b.y), h[10], s); s = fmaf(bfhi(b.y), h[11], s);
    s = fmaf(bflo(b.z), h[12], s); s = fmaf(bfhi(b.z), h[13], s);
    s = fmaf(bflo(b.w), h[14], s); s = fmaf(bfhi(b.w), h[15], s);
    return s;
}

__device__ __forceinline__ void load16(const float* src, int lane, float* d){
    const float4* p = (const float4*)(src + (lane << 4));
    float4 a = p[0], b = p[1], c = p[2], e = p[3];
    d[0]=a.x; d[1]=a.y; d[2]=a.z; d[3]=a.w;
    d[4]=b.x; d[5]=b.y; d[6]=b.z; d[7]=b.w;
    d[8]=c.x; d[9]=c.y; d[10]=c.z; d[11]=c.w;
    d[12]=e.x; d[13]=e.y; d[14]=e.z; d[15]=e.w;
}

// ---------- dtype traits ----------
struct TBF {
    static __device__ __forceinline__ float g(const void* p, int i){ return bf1(((const u16*)p)[i]); }
    static __device__ __forceinline__ const void* rp(const void* p, size_t eoff){ return (const void*)((const u16*)p + eoff); }
    static __device__ __forceinline__ float dot1024(const void* pr, const float* h, int lane){
        const u16* row = (const u16*)pr;
        const uint4* p = (const uint4*)(row + ((size_t)lane << 4));
        uint4 a = p[0], b = p[1];
        return dot16bf(a, b, h);
    }
    static __device__ __forceinline__ float dot512(const void* pr, const float* h8, int lane){
        const u16* row = (const u16*)pr;
        uint4 a = *((const uint4*)(row + ((size_t)lane << 3)));
        float s = 0.f;
        s = fmaf(bflo(a.x), h8[0], s); s = fmaf(bfhi(a.x), h8[1], s);
        s = fmaf(bflo(a.y), h8[2], s); s = fmaf(bfhi(a.y), h8[3], s);
        s = fmaf(bflo(a.z), h8[4], s); s = fmaf(bfhi(a.z), h8[5], s);
        s = fmaf(bflo(a.w), h8[6], s); s = fmaf(bfhi(a.w), h8[7], s);
        return s;
    }
    static __device__ __forceinline__ void vec8(const void* pr, int lane, float* d){
        const u16* src = (const u16*)pr;
        uint4 a = *((const uint4*)(src + ((size_t)lane << 3)));
        d[0]=bflo(a.x); d[1]=bfhi(a.x); d[2]=bflo(a.y); d[3]=bfhi(a.y);
        d[4]=bflo(a.z); d[5]=bfhi(a.z); d[6]=bflo(a.w); d[7]=bfhi(a.w);
    }
    static __device__ __forceinline__ void store(void* o, size_t i, float v){ ((u16*)o)[i] = f2bf(v); }
    static __device__ __forceinline__ void zero(void* o, size_t i){ ((u16*)o)[i] = 0; }
};

struct TF32 {
    static __device__ __forceinline__ float g(const void* p, int i){ return ((const float*)p)[i]; }
    static __device__ __forceinline__ const void* rp(const void* p, size_t eoff){ return (const void*)((const float*)p + eoff); }
    static __device__ __forceinline__ float dot1024(const void* pr, const float* h, int lane){
        const float4* p = (const float4*)((const float*)pr + ((size_t)lane << 4));
        float4 a = p[0], b = p[1], c = p[2], e = p[3];
        float s = 0.f;
        s = fmaf(a.x, h[0],  s); s = fmaf(a.y, h[1],  s); s = fmaf(a.z, h[2],  s); s = fmaf(a.w, h[3],  s);
        s = fmaf(b.x, h[4],  s); s = fmaf(b.y, h[5],  s); s = fmaf(b.z, h[6],  s); s = fmaf(b.w, h[7],  s);
        s = fmaf(c.x, h[8],  s); s = fmaf(c.y, h[9],  s); s = fmaf(c.z, h[10], s); s = fmaf(c.w, h[11], s);
        s = fmaf(e.x, h[12], s); s = fmaf(e.y, h[13], s); s = fmaf(e.z, h[14], s); s = fmaf(e.w, h[15], s);
        return s;
    }
    static __device__ __forceinline__ float dot512(const void* pr, const float* h8, int lane){
        const float4* p = (const float4*)((const float*)pr + ((size_t)lane << 3));
        float4 a = p[0], b = p[1];
        float s = 0.f;
        s = fmaf(a.x, h8[0], s); s = fmaf(a.y, h8[1], s); s = fmaf(a.z, h8[2], s); s = fmaf(a.w, h8[3], s);
        s = fmaf(b.x, h8[4], s); s = fmaf(b.y, h8[5], s); s = fmaf(b.z, h8[6], s); s = fmaf(b.w, h8[7], s);
        return s;
    }
    static __device__ __forceinline__ void vec8(const void* pr, int lane, float* d){
        const float4* p = (const float4*)((const float*)pr + ((size_t)lane << 3));
        float4 a = p[0], b = p[1];
        d[0]=a.x; d[1]=a.y; d[2]=a.z; d[3]=a.w;
        d[4]=b.x; d[5]=b.y; d[6]=b.z; d[7]=b.w;
    }
    static __device__ __forceinline__ void store(void* o, size_t i, float v){ ((float*)o)[i] = v; }
    static __device__ __forceinline__ void zero(void* o, size_t i){ ((float*)o)[i] = 0.f; }
};

// ---------- two-level monotonic grid barrier (NO acquire fence!) ----------
// Release side: waitcnt + writeback of dirty lines (cheap; cross-block data
// is written with sc1 write-through stores). Acquire side: none — consumers
// use per-line-coherent sc1 loads, so L2-resident weights survive the phase.
__device__ __forceinline__ void grid_barrier(u32* bar, u32 tgen, int bid){
    __syncthreads();
    if (threadIdx.x == 0){
        __builtin_amdgcn_fence(__ATOMIC_RELEASE, "agent");
        u32 a = __hip_atomic_fetch_add(&bar[(bid & 7) * 32], 1u,
                                       __ATOMIC_RELAXED, __HIP_MEMORY_SCOPE_AGENT);
        if ((a % 32u) == 31u){
            u32 m = __hip_atomic_fetch_add(&bar[256], 1u,
                                           __ATOMIC_RELAXED, __HIP_MEMORY_SCOPE_AGENT);
            if ((m % 8u) == 7u)
                __hip_atomic_store(&bar[288], tgen, __ATOMIC_RELAXED, __HIP_MEMORY_SCOPE_AGENT);
        }
        while (__hip_atomic_load(&bar[288], __ATOMIC_RELAXED, __HIP_MEMORY_SCOPE_AGENT) < tgen)
            __builtin_amdgcn_s_sleep(1);
        asm volatile("" ::: "memory");   // compiler-only: no reordering past the poll
    }
    __syncthreads();
}

__global__ void ws_init(u32* ws){
    int i = threadIdx.x + blockIdx.x * blockDim.x;
    if (i < 1024) ws[i] = 0u;
}

// probe: decide bf16 (0) vs f32 (1) by scanning emb's u16s as bf16 exponents.
__global__ void dtype_probe(const u16* emb, u32* ws){
    __shared__ int sh[4];
    int tid = threadIdx.x;
    int bad = 0;
    for (int i = tid; i < 2048; i += 256){
        u32 e = ((u32)emb[i] >> 7) & 0xFFu;
        if (e >= 0x82u) bad++;
    }
#pragma unroll
    for (int off = 32; off > 0; off >>= 1) bad += __shfl_xor(bad, off, 64);
    if ((tid & 63) == 0) sh[tid >> 6] = bad;
    __syncthreads();
    if (tid == 0){
        int t = sh[0] + sh[1] + sh[2] + sh[3];
        ws[512] = (t > 8) ? 1u : 0u;
    }
}

template<class W, u32 WANT>
__global__ __launch_bounds__(NT) void dae_main(
    const int* __restrict__ xs, const int* __restrict__ ys,
    const void* __restrict__ emb,
    const void* __restrict__ eWih0, const void* __restrict__ eWhh0,
    const void* __restrict__ ebih0, const void* __restrict__ ebhh0,
    const void* __restrict__ eWih1, const void* __restrict__ eWhh1,
    const void* __restrict__ ebih1, const void* __restrict__ ebhh1,
    const void* __restrict__ efcW,  const void* __restrict__ efcb,
    const void* __restrict__ dWih0, const void* __restrict__ dWhh0,
    const void* __restrict__ dbih0, const void* __restrict__ dbhh0,
    const void* __restrict__ dWih1, const void* __restrict__ dWhh1,
    const void* __restrict__ dbih1, const void* __restrict__ dbhh1,
    const void* __restrict__ dfcW,  const void* __restrict__ dfcb,
    void* __restrict__ out, u32* __restrict__ ws)
{
    if (__hip_atomic_load(&ws[512], __ATOMIC_RELAXED, __HIP_MEMORY_SCOPE_AGENT) != WANT) return;

    const int tid  = threadIdx.x;
    const int bid  = blockIdx.x;
    const int lane = tid & 63;
    const int wave = tid >> 6;

    __shared__ __align__(16) float h0s[HD];
    __shared__ __align__(16) float h1s[HD];
    __shared__ float redmax[8];
    __shared__ int   redidx[8];
    __shared__ float xf_sh;

    u32*   bar  = ws;
    float* G0   = (float*)(ws + 1024);   // [2][4096]
    float* G1   = G0 + 2 * G4;           // [2][4096]
    float* M0   = G1 + 2 * G4;           // [2][4096]
    float* Fv   = M0 + 2 * G4;           // [1024]
    float* bmax = Fv + HD;               // [256]
    int*   bidxv= (int*)(bmax + NB);     // [256]

    u32 phase = 0;
    float c0r[2] = {0.f, 0.f};
    float c1r[2] = {0.f, 0.f};

    for (int i = tid; i < HD; i += NT){ h0s[i] = 0.f; h1s[i] = 0.f; }
    for (int i = tid; i < RPB; i += NT) W::zero(out, (size_t)bid * RPB + i);   // row 0 = zeros

    // ---------------- boot: G0[0] = eWih0 @ emb[x0] + b0 ----------------
    {
        int tok = xs[0];
        float er[8];
        W::vec8(W::rp(emb, (size_t)tok * EDIM), lane, er);
        const int rb = bid * 16 + wave * 2;
#pragma unroll
        for (int i = 0; i < 2; ++i){
            int r = rb + i;
            float s = W::dot512(W::rp(eWih0, (size_t)r * EDIM), er, lane);
            s = wave_sum(s);
            if (lane == 0) gstf(&G0[r], s + W::g(ebih0, r) + W::g(ebhh0, r));
        }
    }
    grid_barrier(bar, ++phase, bid);

    // ---------------- encoder: 1 phase per step (layer-1 lags one step) --
    for (int t = 0; t < SLEN; ++t){
        const int cur = t & 1, nxt = cur ^ 1;
        if (t >= 1){
            const float* Gg = G1 + nxt * G4;
#pragma unroll
            for (int i = 0; i < 2; ++i){
                int r = tid * 2 + i;
                float ig = gldf(&Gg[r]),        fg = gldf(&Gg[r + HD]);
                float gg = gldf(&Gg[r + 2*HD]), og = gldf(&Gg[r + 3*HD]);
                float c = sigm(fg) * c1r[i] + sigm(ig) * tanh_f(gg);
                c1r[i] = c;
                h1s[r] = sigm(og) * tanh_f(c);
            }
        }
        {
            const float* Gg = G0 + cur * G4;
#pragma unroll
            for (int i = 0; i < 2; ++i){
                int r = tid * 2 + i;
                float ig = gldf(&Gg[r]),        fg = gldf(&Gg[r + HD]);
                float gg = gldf(&Gg[r + 2*HD]), og = gldf(&Gg[r + 3*HD]);
                float c = sigm(fg) * c0r[i] + sigm(ig) * tanh_f(gg);
                c0r[i] = c;
                h0s[r] = sigm(og) * tanh_f(c);
            }
        }
        __syncthreads();
        float h0r[16], h1r[16];
        load16(h0s, lane, h0r);
        load16(h1s, lane, h1r);
        const int rb = bid * 16 + wave * 2;
        if (t < SLEN - 1){
            int tok = xs[t + 1];
            float er[8];
            W::vec8(W::rp(emb, (size_t)tok * EDIM), lane, er);
#pragma unroll
            for (int i = 0; i < 2; ++i){
                int r = rb + i;
                float s = W::dot1024(W::rp(eWhh0, (size_t)r * HD), h0r, lane)
                        + W::dot512(W::rp(eWih0, (size_t)r * EDIM), er, lane);
                s = wave_sum(s);
                if (lane == 0) gstf(&G0[nxt * G4 + r], s + W::g(ebih0, r) + W::g(ebhh0, r));
            }
        }
#pragma unroll
        for (int i = 0; i < 2; ++i){
            int r = rb + i;
            float s = W::dot1024(W::rp(eWih1, (size_t)r * HD), h0r, lane)
                    + W::dot1024(W::rp(eWhh1, (size_t)r * HD), h1r, lane);
            s = wave_sum(s);
            if (lane == 0) gstf(&G1[cur * G4 + r], s + W::g(ebih1, r) + W::g(ebhh1, r));
        }
        grid_barrier(bar, ++phase, bid);
    }

    // ---------------- encoder final: h1[511]; F = efcW @ h1 + efcb -------
    {
        const float* Gg = G1 + ((SLEN - 1) & 1) * G4;
#pragma unroll
        for (int i = 0; i < 2; ++i){
            int r = tid * 2 + i;
            float ig = gldf(&Gg[r]),        fg = gldf(&Gg[r + HD]);
            float gg = gldf(&Gg[r + 2*HD]), og = gldf(&Gg[r + 3*HD]);
            float c = sigm(fg) * c1r[i] + sigm(ig) * tanh_f(gg);
            c1r[i] = c;
            h1s[r] = sigm(og) * tanh_f(c);
        }
        __syncthreads();
        float h1r[16];
        load16(h1s, lane, h1r);
        if (wave < 4){
            int r = bid * 4 + wave;
            float s = W::dot1024(W::rp(efcW, (size_t)r * HD), h1r, lane);
            s = wave_sum(s);
            if (lane == 0) gstf(&Fv[r], s + W::g(efcb, r));
        }
        grid_barrier(bar, ++phase, bid);
    }

    // ---------------- decoder boot: lat = relu(F); M0[1] = dWhh0@lat + b0
    {
        for (int i = tid; i < HD; i += NT){
            float v = gldf(&Fv[i]); v = v > 0.f ? v : 0.f;
            h0s[i] = v; h1s[i] = v;
        }
        __syncthreads();
        float h0r[16];
        load16(h0s, lane, h0r);
        const int rb = bid * 16 + wave * 2;
#pragma unroll
        for (int i = 0; i < 2; ++i){
            int r = rb + i;
            float s = W::dot1024(W::rp(dWhh0, (size_t)r * HD), h0r, lane);
            s = wave_sum(s);
            if (lane == 0) gstf(&M0[G4 + r], s + W::g(dbih0, r) + W::g(dbhh0, r));
        }
        grid_barrier(bar, ++phase, bid);
    }

    // ---------------- decoder: 2 phases per step -------------------------
    for (int t = 1; t < 256; ++t){
        // ---- phase P(t): x_f, h0(t); G1d(t), M0(t+1) ----
        float xf;
        if (t == 1){
            xf = (float)ys[0];
        } else {
            if (wave == 0){
                float m = gldf(&bmax[lane]); int mi = gldi(&bidxv[lane]);
#pragma unroll
                for (int j = 64; j < NB; j += 64){
                    float m2 = gldf(&bmax[lane + j]); int i2 = gldi(&bidxv[lane + j]);
                    if (m2 > m || (m2 == m && i2 < mi)){ m = m2; mi = i2; }
                }
#pragma unroll
                for (int off = 32; off > 0; off >>= 1){
                    float m2 = __shfl_xor(m, off, 64);
                    int   i2 = __shfl_xor(mi, off, 64);
                    if (m2 > m || (m2 == m && i2 < mi)){ m = m2; mi = i2; }
                }
                if (lane == 0) xf_sh = (float)mi;
            }
            __syncthreads();
            xf = xf_sh;
        }
        {
            const float* Gg = M0 + (t & 1) * G4;
#pragma unroll
            for (int i = 0; i < 2; ++i){
                int r = tid * 2 + i;
                float ig = gldf(&Gg[r])        + xf * W::g(dWih0, r);
                float fg = gldf(&Gg[r + HD])   + xf * W::g(dWih0, r + HD);
                float gg = gldf(&Gg[r + 2*HD]) + xf * W::g(dWih0, r + 2*HD);
                float og = gldf(&Gg[r + 3*HD]) + xf * W::g(dWih0, r + 3*HD);
                float cp = h0s[r];                       // quirk: c := h
                float c  = sigm(fg) * cp + sigm(ig) * tanh_f(gg);
                h0s[r]   = sigm(og) * tanh_f(c);
            }
        }
        __syncthreads();
        {
            float h0r[16], h1r[16];
            load16(h0s, lane, h0r);
            load16(h1s, lane, h1r);
            const int rb = bid * 16 + wave * 2;
#pragma unroll
            for (int i = 0; i < 2; ++i){
                int r = rb + i;
                float s1 = W::dot1024(W::rp(dWih1, (size_t)r * HD), h0r, lane)
                         + W::dot1024(W::rp(dWhh1, (size_t)r * HD), h1r, lane);
                s1 = wave_sum(s1);
                if (lane == 0) gstf(&G1[(t & 1) * G4 + r], s1 + W::g(dbih1, r) + W::g(dbhh1, r));
                float s0 = W::dot1024(W::rp(dWhh0, (size_t)r * HD), h0r, lane);
                s0 = wave_sum(s0);
                if (lane == 0) gstf(&M0[((t + 1) & 1) * G4 + r], s0 + W::g(dbih0, r) + W::g(dbhh0, r));
            }
        }
        grid_barrier(bar, ++phase, bid);

        // ---- phase Q(t): h1(t); logits(t) + per-block argmax ----
        {
            const float* Gg = G1 + (t & 1) * G4;
#pragma unroll
            for (int i = 0; i < 2; ++i){
                int r = tid * 2 + i;
                float ig = gldf(&Gg[r]),        fg = gldf(&Gg[r + HD]);
                float gg = gldf(&Gg[r + 2*HD]), og = gldf(&Gg[r + 3*HD]);
                float cp = h1s[r];                       // quirk: c := h
                float c  = sigm(fg) * cp + sigm(ig) * tanh_f(gg);
                h1s[r]   = sigm(og) * tanh_f(c);
            }
        }
        __syncthreads();
        {
            float h1r[16];
            load16(h1s, lane, h1r);
            float wmax = -3.4e38f; int wmi = 0x7fffffff;
            int i = wave;
            // 2-row interleave: doubles vmem MLP in the streaming fcW loop.
            for (; i + 8 < RPB; i += 16){
                int r1 = bid * RPB + i, r2 = r1 + 8;
                float s1 = W::dot1024(W::rp(dfcW, (size_t)r1 * HD), h1r, lane);
                float s2 = W::dot1024(W::rp(dfcW, (size_t)r2 * HD), h1r, lane);
                s1 = wave_sum(s1); s2 = wave_sum(s2);
                s1 += W::g(dfcb, r1); s2 += W::g(dfcb, r2);
                if (lane == 0){
                    W::store(out, (size_t)t * VOCAB + r1, s1);
                    W::store(out, (size_t)t * VOCAB + r2, s2);
                }
                if (s1 > wmax){ wmax = s1; wmi = r1; }   // ascending rows: '>' keeps first
                if (s2 > wmax){ wmax = s2; wmi = r2; }
            }
            if (i < RPB){
                int r = bid * RPB + i;
                float s = W::dot1024(W::rp(dfcW, (size_t)r * HD), h1r, lane);
                s = wave_sum(s) + W::g(dfcb, r);
                if (lane == 0) W::store(out, (size_t)t * VOCAB + r, s);
                if (s > wmax){ wmax = s; wmi = r; }
            }
            if (lane == 0){ redmax[wave] = wmax; redidx[wave] = wmi; }
        }
        __syncthreads();
        if (tid == 0){
            float m = redmax[0]; int mi = redidx[0];
#pragma unroll
            for (int w = 1; w < 8; ++w){
                if (redmax[w] > m || (redmax[w] == m && redidx[w] < mi)){ m = redmax[w]; mi = redidx[w]; }
            }
            gstf(&bmax[bid], m); gsti(&bidxv[bid], mi);
        }
        grid_barrier(bar, ++phase, bid);
    }
}

extern "C" void kernel_launch(void* const* d_in, const int* in_sizes, int n_in,
                              void* d_out, int out_size, void* d_ws, size_t ws_size,
                              hipStream_t stream) {
    const int* xs = (const int*)d_in[0];
    const int* ys = (const int*)d_in[1];
    u32* ws = (u32*)d_ws;

    ws_init<<<4, 256, 0, stream>>>(ws);
    dtype_probe<<<1, 256, 0, stream>>>((const u16*)d_in[2], ws);

    dae_main<TBF, 0u><<<NB, NT, 0, stream>>>(
        xs, ys, d_in[2],
        d_in[3], d_in[4], d_in[5], d_in[6], d_in[7], d_in[8], d_in[9], d_in[10],
        d_in[11], d_in[12],
        d_in[13], d_in[14], d_in[15], d_in[16], d_in[17], d_in[18], d_in[19], d_in[20],
        d_in[21], d_in[22],
        d_out, ws);
    dae_main<TF32, 1u><<<NB, NT, 0, stream>>>(
        xs, ys, d_in[2],
        d_in[3], d_in[4], d_in[5], d_in[6], d_in[7], d_in[8], d_in[9], d_in[10],
        d_in[11], d_in[12],
        d_in[13], d_in[14], d_in[15], d_in[16], d_in[17], d_in[18], d_in[19], d_in[20],
        d_in[21], d_in[22],
        d_out, ws);
}